// Round 16
// baseline (669.195 us; speedup 1.0000x reference)
//
#include <hip/hip_runtime.h>
#include <cstddef>
#include <cstdint>

typedef unsigned short ushort_t;

constexpr int B_ = 64, L_ = 80, E_ = 256, H_ = 256, C_ = 4, DT_ = 100;
constexpr int N_ = B_ * L_;          // 5120
constexpr int G4_ = 4 * H_;          // 1024
constexpr int DH2_ = 2 * H_;         // 512
constexpr int DF_ = 4 * L_ * H_;     // 81920
constexpr float EPS_ = 1e-5f;
constexpr int FB_USH = 8192;         // ushorts per (grp,par) fragment region (16 KB)

typedef short s8v __attribute__((ext_vector_type(8)));
typedef float f4v __attribute__((ext_vector_type(4)));
typedef ushort_t us8 __attribute__((ext_vector_type(8)));

__device__ inline ushort_t f2bf_rn(float x) {
    uint32_t u = __builtin_bit_cast(uint32_t, x);
    uint32_t r = (u + 0x7fffu + ((u >> 16) & 1u)) >> 16;
    return (ushort_t)r;
}
__device__ inline float bf2f(ushort_t h) {
    uint32_t u = ((uint32_t)h) << 16;
    return __builtin_bit_cast(float, u);
}
__device__ inline float bf2f_lo(uint32_t u) { return __builtin_bit_cast(float, u << 16); }
__device__ inline float bf2f_hi(uint32_t u) { return __builtin_bit_cast(float, u & 0xffff0000u); }
__device__ inline float rcpf(float x) { return __builtin_amdgcn_rcpf(x); }
__device__ inline float sigm(float x) { return rcpf(1.f + __expf(-x)); }
__device__ inline float tanh_fast(float x) {
    float e2 = __expf(2.f * x);
    return 1.f - 2.f * rcpf(1.f + e2);
}

#define MFMA_B16(a, b, c) __builtin_amdgcn_mfma_f32_16x16x32_bf16((a), (b), (c), 0, 0, 0)

// ---------------------------------------------------------------------------
// Merged preprocessing:
//  [0,10240)      embed -> ehi/elo split planes
//  [10240,11264)  Rt pack + bcat
//  [11264,13312)  Whh -> MFMA B-fragments (split)
//  [13312,15360)  Wih(cat) -> MFMA B-fragments (split)   [NEW: frag order]
//  [15360,15424)  init fragbuf + flags
//  15424          rel matrix
__global__ void k_prep(const int* __restrict__ arg1, const int* __restrict__ arg2,
                       const float* __restrict__ table,
                       const float* __restrict__ tE1, const float* __restrict__ tE2,
                       const float* __restrict__ Wih_f, const float* __restrict__ Wih_b,
                       const float* __restrict__ bih_f, const float* __restrict__ bhh_f,
                       const float* __restrict__ bih_b, const float* __restrict__ bhh_b,
                       const float* __restrict__ R,
                       const float* __restrict__ Whh_f, const float* __restrict__ Whh_b,
                       ushort_t* __restrict__ ehi, ushort_t* __restrict__ elo,
                       float* __restrict__ bcat,
                       ushort_t* __restrict__ Rthi, ushort_t* __restrict__ Rtlo,
                       ushort_t* __restrict__ Bhi, ushort_t* __restrict__ Blo,
                       ushort_t* __restrict__ Fhi, ushort_t* __restrict__ Flo,
                       ushort_t* __restrict__ fragbuf, int* __restrict__ flags,
                       float* __restrict__ rel) {
    __shared__ float m1[80], m2[80];
    int blk = blockIdx.x;
    int tid = threadIdx.x;
    if (blk < 10240) {
        int r = blk;
        int rr = (r >= N_) ? (r - N_) : r;
        int idx = (r >= N_) ? arg2[rr] : arg1[rr];
        float v = table[(size_t)idx * E_ + tid];
        ushort_t h = f2bf_rn(v);
        ehi[(size_t)r * E_ + tid] = h;
        elo[(size_t)r * E_ + tid] = f2bf_rn(v - bf2f(h));
    } else if (blk < 11264) {
        int i = (blk - 10240) * 256 + tid;
        if (i < 2 * G4_)
            bcat[i] = (i < G4_) ? (bih_f[i] + bhh_f[i]) : (bih_b[i - G4_] + bhh_b[i - G4_]);
        if (i < 512 * 512) {
            int m = i >> 9, k = i & 511;
            float v = R[k * 512 + m];
            ushort_t h = f2bf_rn(v);
            Rthi[i] = h;
            Rtlo[i] = f2bf_rn(v - bf2f(h));
        }
    } else if (blk < 13312) {
        int idx = (blk - 11264) * 256 + tid;   // < 524288
        int e = idx & 7;
        int lane = (idx >> 3) & 63;
        int g = (idx >> 9) & 3;
        int kt = (idx >> 11) & 7;
        int w = (idx >> 14) & 15;
        int d = idx >> 18;
        int c = lane & 15, q = lane >> 4;
        int row = g * 256 + w * 16 + c;
        int k = kt * 32 + q * 8 + e;
        const float* W = d ? Whh_b : Whh_f;
        float v = W[row * 256 + k];
        ushort_t hi = f2bf_rn(v);
        Bhi[idx] = hi;
        Blo[idx] = f2bf_rn(v - bf2f(hi));
    } else if (blk < 15360) {
        int idx = (blk - 13312) * 256 + tid;   // < 524288
        int e = idx & 7;
        int lane = (idx >> 3) & 63;
        int g = (idx >> 9) & 3;
        int kt = (idx >> 11) & 7;
        int w = (idx >> 14) & 15;
        int d = idx >> 18;
        int c = lane & 15, q = lane >> 4;
        int row = g * 256 + w * 16 + c;        // row within direction's Wih [1024][256]
        int k = kt * 32 + q * 8 + e;
        const float* W = d ? Wih_b : Wih_f;
        float v = W[row * 256 + k];
        ushort_t hi = f2bf_rn(v);
        Fhi[idx] = hi;
        Flo[idx] = f2bf_rn(v - bf2f(hi));
    } else if (blk < 15424) {
        int i = (blk - 15360) * 256 + tid;
        if (i < 1024) flags[i] = 0;
        uint4* p = (uint4*)fragbuf;
        for (int jj = i; jj < 32768; jj += 64 * 256)
            p[jj] = make_uint4(0u, 0u, 0u, 0u);
    } else {
        if (tid < 80) {
            float s = 0.f;
            for (int k = 0; k < DT_; ++k) s += tE1[tid * DT_ + k];
            m1[tid] = s * (1.0f / DT_);
        } else if (tid < 160) {
            int i = tid - 80;
            float s = 0.f;
            for (int k = 0; k < DT_; ++k) s += tE2[i * DT_ + k];
            m2[i] = s * (1.0f / DT_);
        }
        __syncthreads();
        for (int idx = tid; idx < 80 * 80; idx += 256)
            rel[idx] = tanhf(m1[idx / 80] - m2[idx % 80]);
    }
}

// ---------------------------------------------------------------------------
// Persistent flag-dataflow LSTM v10 = v9c's LOCKED sync protocol (block
// barrier D -> single flag -> one polling wave -> barrier A; distributed
// variants regressed 3x) + xg FOLDED IN: each wave holds Wih B-fragments
// resident and computes preact = e*Wih + h*Whh in one MFMA accumulation,
// using the otherwise-idle matrix pipe. e A-fragments are loaded per step
// from the e planes BEFORE the flag poll (latency hidden under the stall).
// Kills the standalone xg GEMM and its 168 MB of xg traffic.
__global__ __launch_bounds__(256, 2) void k_lstm10(
        const ushort_t* __restrict__ ehi, const ushort_t* __restrict__ elo,
        const ushort_t* __restrict__ Bhi, const ushort_t* __restrict__ Blo,
        const ushort_t* __restrict__ Fhi, const ushort_t* __restrict__ Flo,
        const float* __restrict__ bcat,
        ushort_t* __restrict__ o1hi, ushort_t* __restrict__ o1lo,
        ushort_t* __restrict__ o2hi, ushort_t* __restrict__ o2lo,
        ushort_t* __restrict__ fragbuf, int* __restrict__ flags) {
    const int bid = blockIdx.x;          // 0..255
    const int s = bid & 15;
    const int cg = (bid >> 4) & 7;
    const int d = bid >> 7;
    const int tid = threadIdx.x;         // 0..255
    const int g = tid >> 6, lane = tid & 63;
    const int c16 = lane & 15, qq = lane >> 4;

    __shared__ __align__(16) ushort_t Abuf[8192];   // 16 KB
    __shared__ float pre[4][16][16];                // 4 KB

    // resident W fragments: Whh (bh/bl) + Wih (fh/fl), gate g, slice s
    s8v bh[8], bl[8], fh[8], fl[8];
    {
        const s8v* BH = (const s8v*)Bhi;
        const s8v* BL = (const s8v*)Blo;
        const s8v* FH = (const s8v*)Fhi;
        const s8v* FL = (const s8v*)Flo;
        int base = (d * 16 + s) * 2048 + g * 64 + lane;
        #pragma unroll
        for (int kt = 0; kt < 8; ++kt) {
            bh[kt] = BH[base + kt * 256];
            bl[kt] = BL[base + kt * 256];
            fh[kt] = FH[base + kt * 256];
            fl[kt] = FL[base + kt * 256];
        }
    }

    // combine-phase role: thread owns (chain c_loc, jh j)
    const int c_loc = tid >> 4, j = tid & 15;
    const int kglob = s * 16 + j;
    const int p_kt = kglob >> 5;
    const int p_q = (kglob & 31) >> 3, p_e = kglob & 7;
    const int p_lane = c_loc | (p_q << 4);
    const int fb_off = (p_kt * 64 + p_lane) * 8 + p_e;     // < 4096
    const int cc = cg * 16 + c_loc;
    const int w = cc >> 6, bb = cc & 63;
    ushort_t* ophi = w ? o2hi : o1hi;
    ushort_t* oplo = w ? o2lo : o1lo;
    float cst = 0.f;

    // per-thread gate biases (combine role)
    float bias4[4];
    #pragma unroll
    for (int gg = 0; gg < 4; ++gg) bias4[gg] = bcat[d * G4_ + gg * 256 + kglob];

    // MFMA-role e fragment row base: lane's A-row chain = c16
    const int ccA = cg * 16 + c16;
    const int wA = ccA >> 6, bbA = ccA & 63;
    const size_t erowbase = (size_t)(wA * N_ + bbA * L_) * E_ + qq * 8;

    const int grp = bid >> 4;
    int* gflags = flags + grp * 16;
    const size_t fbbase = (size_t)grp * 2 * FB_USH;

    for (int t = 0; t < L_; ++t) {
        int l = d ? (L_ - 1 - t) : t;

        // e A-fragments for this step (independent of exchange) -- issue early
        s8v eah[8], eal[8];
        {
            const size_t eoff = erowbase + (size_t)l * E_;
            #pragma unroll
            for (int kt = 0; kt < 8; ++kt) {
                eah[kt] = *(const s8v*)(ehi + eoff + kt * 32);
                eal[kt] = *(const s8v*)(elo + eoff + kt * 32);
            }
        }

        if (t > 0) {
            if (tid < 16) {
                while (__hip_atomic_load(&gflags[tid], __ATOMIC_RELAXED,
                                         __HIP_MEMORY_SCOPE_AGENT) < t)
                    __builtin_amdgcn_s_sleep(2);
            }
            __syncthreads();             // bar A: all producers done
        }

        {
            const unsigned long long* src = (const unsigned long long*)(fragbuf
                + fbbase + (size_t)(t & 1) * FB_USH);
            unsigned long long* dst = (unsigned long long*)Abuf;
            #pragma unroll
            for (int r = 0; r < 8; ++r)
                dst[r * 256 + tid] = __hip_atomic_load(
                    &src[r * 256 + tid], __ATOMIC_RELAXED,
                    __HIP_MEMORY_SCOPE_AGENT);
        }
        __syncthreads();                 // bar B: A staged

        // preact = e*Wih + h*Whh (both split-bf16, 3 terms each)
        f4v acc = {0.f, 0.f, 0.f, 0.f};
        #pragma unroll
        for (int kt = 0; kt < 8; ++kt) {
            acc = MFMA_B16(eah[kt], fh[kt], acc);
            acc = MFMA_B16(eah[kt], fl[kt], acc);
            acc = MFMA_B16(eal[kt], fh[kt], acc);
        }
        {
            const s8v* AH = (const s8v*)&Abuf[0];
            const s8v* AL = (const s8v*)&Abuf[4096];
            #pragma unroll
            for (int kt = 0; kt < 8; ++kt) {
                s8v ah = AH[kt * 64 + lane];
                s8v al = AL[kt * 64 + lane];
                acc = MFMA_B16(ah, bh[kt], acc);
                acc = MFMA_B16(ah, bl[kt], acc);
                acc = MFMA_B16(al, bh[kt], acc);
            }
        }
        #pragma unroll
        for (int r = 0; r < 4; ++r)
            pre[g][qq * 4 + r][c16] = acc[r];
        __syncthreads();                 // bar C: pre visible

        ushort_t hh, hl;
        size_t oidx;
        {
            float pi = pre[0][c_loc][j] + bias4[0];
            float pf = pre[1][c_loc][j] + bias4[1];
            float pg = pre[2][c_loc][j] + bias4[2];
            float po = pre[3][c_loc][j] + bias4[3];
            float si = sigm(pi), sf_ = sigm(pf), so = sigm(po);
            cst = sf_ * cst + si * tanh_fast(pg);
            float h = so * tanh_fast(cst);
            oidx = (size_t)(bb * L_ + l) * DH2_ + d * H_ + kglob;
            hh = f2bf_rn(h);
            hl = f2bf_rn(h - bf2f(hh));
            ushort_t* fbn = fragbuf + fbbase + (size_t)((t + 1) & 1) * FB_USH;
            __hip_atomic_store(&fbn[fb_off], hh, __ATOMIC_RELAXED,
                               __HIP_MEMORY_SCOPE_AGENT);
            __hip_atomic_store(&fbn[4096 + fb_off], hl, __ATOMIC_RELAXED,
                               __HIP_MEMORY_SCOPE_AGENT);
        }
        __syncthreads();                 // bar D: frag stores drained block-wide

        if (tid == 0)
            __hip_atomic_store(&flags[bid], t + 1, __ATOMIC_RELAXED,
                               __HIP_MEMORY_SCOPE_AGENT);

        ophi[oidx] = hh;                 // off-critical-path
        oplo[oidx] = hl;
    }
}

// ---------------------------------------------------------------------------
// Generic split-bf16 MFMA GEMM: C = A * Bt^T (+bias). 128x128 tile, 1-D grid
// with XCD-chunked swizzle.
__global__ __launch_bounds__(256) void k_gemm_bf(
        const ushort_t* __restrict__ Ahi, const ushort_t* __restrict__ Alo,
        const ushort_t* __restrict__ Bthi, const ushort_t* __restrict__ Btlo,
        const float* __restrict__ bias, float* __restrict__ Cout,
        ushort_t* __restrict__ Couthi, ushort_t* __restrict__ Coutlo,
        int M, int Nn, int K) {
    __shared__ ushort_t smpool[4][4096];        // 32 KB
    const int tid = threadIdx.x;
    const int w = tid >> 6, lane = tid & 63;
    const int wr = w >> 1, wc = w & 1;
    const int c16 = lane & 15, q4 = lane >> 4;
    const int nbx = Nn >> 7;
    const int cpx = ((M >> 7) * nbx) >> 3;
    const int fid = blockIdx.x;
    const int swz = (fid & 7) * cpx + (fid >> 3);
    const int bx = swz % nbx, by = swz / nbx;
    const int r0 = by * 128, c0 = bx * 128;

    f4v acc[4][4] = {};
    const ushort_t* planes[4] = {
        Ahi + (size_t)r0 * K, Alo + (size_t)r0 * K,
        Bthi + (size_t)c0 * K, Btlo + (size_t)c0 * K };

    for (int kk = 0; kk < K; kk += 32) {
        #pragma unroll
        for (int p = 0; p < 4; ++p) {
            const ushort_t* src = planes[p] + kk;
            #pragma unroll
            for (int it = 0; it < 2; ++it) {
                int idx = it * 256 + tid;
                int row = idx >> 2, q = idx & 3;
                *(us8*)&smpool[p][(q * 128 + row) * 8] =
                    *(const us8*)&src[(size_t)row * K + q * 8];
            }
        }
        __syncthreads();
        s8v ah[4], al[4], bhv[4], blv[4];
        #pragma unroll
        for (int mi = 0; mi < 4; ++mi) {
            int ar = wr * 64 + mi * 16 + c16;
            ah[mi] = *(const s8v*)&smpool[0][(q4 * 128 + ar) * 8];
            al[mi] = *(const s8v*)&smpool[1][(q4 * 128 + ar) * 8];
        }
        #pragma unroll
        for (int ni = 0; ni < 4; ++ni) {
            int br = wc * 64 + ni * 16 + c16;
            bhv[ni] = *(const s8v*)&smpool[2][(q4 * 128 + br) * 8];
            blv[ni] = *(const s8v*)&smpool[3][(q4 * 128 + br) * 8];
        }
        #pragma unroll
        for (int mi = 0; mi < 4; ++mi)
            #pragma unroll
            for (int ni = 0; ni < 4; ++ni) {
                acc[mi][ni] = MFMA_B16(ah[mi], bhv[ni], acc[mi][ni]);
                acc[mi][ni] = MFMA_B16(ah[mi], blv[ni], acc[mi][ni]);
                acc[mi][ni] = MFMA_B16(al[mi], bhv[ni], acc[mi][ni]);
            }
        __syncthreads();
    }
    #pragma unroll
    for (int mi = 0; mi < 4; ++mi)
        #pragma unroll
        for (int rg = 0; rg < 4; ++rg) {
            int row = r0 + wr * 64 + mi * 16 + q4 * 4 + rg;
            #pragma unroll
            for (int ni = 0; ni < 4; ++ni) {
                int col = c0 + wc * 64 + ni * 16 + c16;
                float v = acc[mi][ni][rg] + (bias ? bias[col] : 0.f);
                size_t idx = (size_t)row * Nn + col;
                if (Couthi) {
                    ushort_t h = f2bf_rn(v);
                    Couthi[idx] = h;
                    Coutlo[idx] = f2bf_rn(v - bf2f(h));
                } else {
                    Cout[idx] = v;
                }
            }
        }
}

// ---------------------------------------------------------------------------
// MFMA k_big: E = exp(tanh(u t2^T) + kg) stored bf16; sums of ROUNDED values.
__global__ __launch_bounds__(256) void k_bigm(
        const ushort_t* __restrict__ uhi, const ushort_t* __restrict__ ulo,
        const ushort_t* __restrict__ vhi, const ushort_t* __restrict__ vlo,
        const float* __restrict__ rel, ushort_t* __restrict__ Ebf,
        float* __restrict__ rowpart, float* __restrict__ colpart) {
    __shared__ ushort_t smpool[4][4096];        // 32 KB
    const int tid = threadIdx.x;
    const int w = tid >> 6, lane = tid & 63;
    const int wr = w >> 1, wc = w & 1;
    const int c16 = lane & 15, q4 = lane >> 4;
    const int fid = blockIdx.x;                 // 1600 = 8 * 200
    const int swz = (fid & 7) * 200 + (fid >> 3);
    const int bx = swz % 40, by = swz / 40;
    const int r0 = by * 128, c0 = bx * 128;

    f4v acc[4][4] = {};
    const ushort_t* planes[4] = {
        uhi + (size_t)r0 * DH2_, ulo + (size_t)r0 * DH2_,
        vhi + (size_t)c0 * DH2_, vlo + (size_t)c0 * DH2_ };

    for (int kk = 0; kk < 16; ++kk) {
        #pragma unroll
        for (int p = 0; p < 4; ++p) {
            const ushort_t* src = planes[p] + kk * 32;
            #pragma unroll
            for (int it = 0; it < 2; ++it) {
                int idx = it * 256 + tid;
                int row = idx >> 2, q = idx & 3;
                *(us8*)&smpool[p][(q * 128 + row) * 8] =
                    *(const us8*)&src[(size_t)row * DH2_ + q * 8];
            }
        }
        __syncthreads();
        s8v ah[4], al[4], bhv[4], blv[4];
        #pragma unroll
        for (int mi = 0; mi < 4; ++mi) {
            int ar = wr * 64 + mi * 16 + c16;
            ah[mi] = *(const s8v*)&smpool[0][(q4 * 128 + ar) * 8];
            al[mi] = *(const s8v*)&smpool[1][(q4 * 128 + ar) * 8];
        }
        #pragma unroll
        for (int ni = 0; ni < 4; ++ni) {
            int br = wc * 64 + ni * 16 + c16;
            bhv[ni] = *(const s8v*)&smpool[2][(q4 * 128 + br) * 8];
            blv[ni] = *(const s8v*)&smpool[3][(q4 * 128 + br) * 8];
        }
        #pragma unroll
        for (int mi = 0; mi < 4; ++mi)
            #pragma unroll
            for (int ni = 0; ni < 4; ++ni) {
                acc[mi][ni] = MFMA_B16(ah[mi], bhv[ni], acc[mi][ni]);
                acc[mi][ni] = MFMA_B16(ah[mi], blv[ni], acc[mi][ni]);
                acc[mi][ni] = MFMA_B16(al[mi], bhv[ni], acc[mi][ni]);
            }
        __syncthreads();
    }

    float* rowred = (float*)&smpool[0][0];      // [128][32]
    float* colred = rowred + 128 * 32;          // [128][8]

    int gcolv[4], bjv[4], ljv[4];
    #pragma unroll
    for (int ni = 0; ni < 4; ++ni) {
        int coll = wc * 64 + ni * 16 + c16;
        gcolv[ni] = c0 + coll;
        bjv[ni] = gcolv[ni] / 80;
        ljv[ni] = gcolv[ni] - bjv[ni] * 80;
    }
    float csumv[4] = {0.f, 0.f, 0.f, 0.f};
    #pragma unroll
    for (int mi = 0; mi < 4; ++mi) {
        #pragma unroll
        for (int rg = 0; rg < 4; ++rg) {
            int rowl = wr * 64 + mi * 16 + q4 * 4 + rg;
            int grow = r0 + rowl;
            int bi = grow / 80, li = grow - bi * 80;
            float rsum = 0.f;
            #pragma unroll
            for (int ni = 0; ni < 4; ++ni) {
                float v = tanhf(acc[mi][ni][rg]);
                if (bi == bjv[ni]) v += rel[li * 80 + ljv[ni]];
                ushort_t eb = f2bf_rn(__expf(v));
                Ebf[(size_t)grow * N_ + gcolv[ni]] = eb;
                float er = bf2f(eb);
                rsum += er;
                csumv[ni] += er;
            }
            rowred[rowl * 32 + wc * 16 + c16] = rsum;
        }
    }
    #pragma unroll
    for (int ni = 0; ni < 4; ++ni) {
        int coll = wc * 64 + ni * 16 + c16;
        colred[coll * 8 + wr * 4 + q4] = csumv[ni];
    }
    __syncthreads();
    if (tid < 128) {
        float ssum = 0.f;
        #pragma unroll
        for (int t = 0; t < 32; ++t) ssum += rowred[tid * 32 + t];
        rowpart[(size_t)bx * N_ + r0 + tid] = ssum;
    } else {
        int c = tid - 128;
        float ssum = 0.f;
        #pragma unroll
        for (int t = 0; t < 8; ++t) ssum += colred[c * 8 + t];
        colpart[(size_t)by * N_ + c0 + c] = ssum;
    }
}

// ---------------------------------------------------------------------------
__global__ void k_redsum(const float* __restrict__ rowpart, const float* __restrict__ colpart,
                         float* __restrict__ rowinv, float* __restrict__ colinv) {
    int i = blockIdx.x * blockDim.x + threadIdx.x;
    if (i < N_) {
        float rs = 0.f, cs = 0.f;
        for (int t = 0; t < 40; ++t) {
            rs += rowpart[(size_t)t * N_ + i];
            cs += colpart[(size_t)t * N_ + i];
        }
        rowinv[i] = 1.f / rs;
        colinv[i] = 1.f / cs;
    }
}

// ---------------------------------------------------------------------------
// Merged sf pass: blocks 0..5119 = sf2 rows (one block/row, LDS tree);
// blocks 5120..5279 = sf1 chunks (col-pair registers over 320-row chunks).
__global__ __launch_bounds__(256) void k_sfboth(
        const ushort_t* __restrict__ Ebf,
        const float* __restrict__ rowinv, const float* __restrict__ colinv,
        float* __restrict__ sf1part, float* __restrict__ sf2) {
    if (blockIdx.x < N_) {
        int i = blockIdx.x;
        const uint32_t* Erow = (const uint32_t*)(Ebf + (size_t)i * N_);
        float p = 0.f;
        #pragma unroll 2
        for (int j2 = threadIdx.x; j2 < N_ / 2; j2 += 256) {
            uint32_t u = Erow[j2];
            p += bf2f_lo(u) * colinv[j2 * 2] + bf2f_hi(u) * colinv[j2 * 2 + 1];
        }
        __shared__ float red[256];
        red[threadIdx.x] = p;
        __syncthreads();
        for (int ss = 128; ss > 0; ss >>= 1) {
            if (threadIdx.x < ss) red[threadIdx.x] += red[threadIdx.x + ss];
            __syncthreads();
        }
        if (threadIdx.x == 0) sf2[i] = red[0] * (1.f / N_);
    } else {
        int b2 = blockIdx.x - N_;                 // 0..159
        int cpb = b2 % 10, rc = b2 / 10;
        int cp = cpb * 256 + threadIdx.x;         // column pair 0..2559
        int r0 = rc * 320;
        float a0 = 0.f, a1 = 0.f;
        #pragma unroll 4
        for (int ii = 0; ii < 320; ++ii) {
            int row = r0 + ii;
            uint32_t u = *(const uint32_t*)(Ebf + (size_t)row * N_ + cp * 2);
            float rinv = rowinv[row];
            a0 += bf2f_lo(u) * rinv;
            a1 += bf2f_hi(u) * rinv;
        }
        sf1part[(size_t)rc * N_ + cp * 2] = a0;
        sf1part[(size_t)rc * N_ + cp * 2 + 1] = a1;
    }
}

__global__ void k_sf1red(const float* __restrict__ sf1part, float* __restrict__ sf1) {
    int jj = blockIdx.x * blockDim.x + threadIdx.x;
    if (jj < N_) {
        float s = 0.f;
        for (int t = 0; t < 16; ++t) s += sf1part[(size_t)t * N_ + jj];
        sf1[jj] = s * (1.f / N_);
    }
}

// ---------------------------------------------------------------------------
__global__ void k_bnstats(const ushort_t* __restrict__ o1hi, const ushort_t* __restrict__ o1lo,
                          const ushort_t* __restrict__ o2hi, const ushort_t* __restrict__ o2lo,
                          const float* __restrict__ sf1, const float* __restrict__ sf2,
                          float* __restrict__ bnmu, float* __restrict__ bnrstd) {
    int f = blockIdx.x * 256 + threadIdx.x;
    int seg = f / (L_ * DH2_);
    int rem = f - seg * (L_ * DH2_);
    int l = rem >> 9, hh = rem & 511;
    const ushort_t* phi = seg ? o2hi : o1hi;
    const ushort_t* plo = seg ? o2lo : o1lo;
    const float* sf = seg ? sf1 : sf2;
    float s = 0.f, s2 = 0.f;
    for (int b = 0; b < B_; ++b) {
        int row = b * L_ + l;
        size_t idx = (size_t)row * DH2_ + hh;
        float x = (bf2f(phi[idx]) + bf2f(plo[idx])) * sf[row];
        s += x;
        s2 += x * x;
    }
    float mu = s * (1.f / B_);
    float v = fmaxf(s2 * (1.f / B_) - mu * mu, 0.f);
    bnmu[f] = mu;
    bnrstd[f] = rsqrtf(v + EPS_);
}

// ---------------------------------------------------------------------------
__global__ __launch_bounds__(256) void k_logits1(
        const ushort_t* __restrict__ o1hi, const ushort_t* __restrict__ o1lo,
        const ushort_t* __restrict__ o2hi, const ushort_t* __restrict__ o2lo,
        const float* __restrict__ sf1, const float* __restrict__ sf2,
        const float* __restrict__ bnmu, const float* __restrict__ bnrstd,
        const float* __restrict__ gamma, const float* __restrict__ beta,
        const float* __restrict__ fcW, float* __restrict__ part) {
    int b = blockIdx.x, ch = blockIdx.y;
    int tid = threadIdx.x;
    int f0 = ch * (DF_ / 5);
    float acc[4] = {0.f, 0.f, 0.f, 0.f};
    for (int f = f0 + tid; f < f0 + DF_ / 5; f += 256) {
        int seg = f / (L_ * DH2_);
        int rem = f - seg * (L_ * DH2_);
        int l = rem >> 9, hh = rem & 511;
        int row = b * L_ + l;
        size_t idx = (size_t)row * DH2_ + hh;
        const ushort_t* phi = seg ? o2hi : o1hi;
        const ushort_t* plo = seg ? o2lo : o1lo;
        float val = (bf2f(phi[idx]) + bf2f(plo[idx])) * (seg ? sf1 : sf2)[row];
        float xn = (val - bnmu[f]) * bnrstd[f] * gamma[f] + beta[f];
        #pragma unroll
        for (int c = 0; c < 4; ++c) acc[c] += xn * fcW[(size_t)c * DF_ + f];
    }
    __shared__ float red[4][257];
    #pragma unroll
    for (int c = 0; c < 4; ++c) red[c][tid] = acc[c];
    __syncthreads();
    for (int ss = 128; ss > 0; ss >>= 1) {
        if (tid < ss)
            #pragma unroll
            for (int c = 0; c < 4; ++c) red[c][tid] += red[c][tid + ss];
        __syncthreads();
    }
    if (tid < 4) part[((size_t)b * 5 + ch) * 4 + tid] = red[tid][0];
}

__global__ void k_logits2(const float* __restrict__ part,
                          const float* __restrict__ fcb,
                          float* __restrict__ dout) {
    int b = blockIdx.x;
    if (threadIdx.x == 0) {
        float lg[4], mx = -1e30f;
        #pragma unroll
        for (int c = 0; c < 4; ++c) {
            float v = fcb[c];
            for (int ch = 0; ch < 5; ++ch) v += part[((size_t)b * 5 + ch) * 4 + c];
            lg[c] = v;
            mx = fmaxf(mx, v);
        }
        float se = 0.f;
        #pragma unroll
        for (int c = 0; c < 4; ++c) se += expf(lg[c] - mx);
        float lse = mx + logf(se);
        #pragma unroll
        for (int c = 0; c < 4; ++c) dout[b * 4 + c] = lg[c] - lse;
    }
}

// ---------------------------------------------------------------------------
extern "C" void kernel_launch(void* const* d_in, const int* in_sizes, int n_in,
                              void* d_out, int out_size, void* d_ws, size_t ws_size,
                              hipStream_t stream) {
    const int* arg1 = (const int*)d_in[0];
    const int* arg2 = (const int*)d_in[1];
    const float* tE1 = (const float*)d_in[3];
    const float* tE2 = (const float*)d_in[4];
    const float* table = (const float*)d_in[5];
    const float* Wih_f = (const float*)d_in[6];
    const float* Whh_f = (const float*)d_in[7];
    const float* bih_f = (const float*)d_in[8];
    const float* bhh_f = (const float*)d_in[9];
    const float* Wih_b = (const float*)d_in[10];
    const float* Whh_b = (const float*)d_in[11];
    const float* bih_b = (const float*)d_in[12];
    const float* bhh_b = (const float*)d_in[13];
    const float* R = (const float*)d_in[14];
    const float* gamma = (const float*)d_in[15];
    const float* beta = (const float*)d_in[16];
    const float* fcW = (const float*)d_in[17];
    const float* fcb = (const float*)d_in[18];
    float* dout = (float*)d_out;

    float* ws = (float*)d_ws;
    size_t off = 0;
    auto alloc = [&](size_t n) { float* p = ws + off; off += n; return p; };

    constexpr size_t PL = (size_t)N_ * DH2_;        // 2,621,440 elements/plane

    float* rel = alloc(80 * 80);
    float* eplanes = alloc((size_t)2 * N_ * E_);    // ehi+elo (LIVE through LSTM)
    float* bcat = alloc(2 * G4_);
    float* Rtplanes = alloc((size_t)262144);        // Rthi+Rtlo
    float* planesA = alloc(PL);                     // o1hi+o1lo
    float* planesO2 = alloc(PL);                    // o2hi+o2lo (dedicated!)
    float* planesU = alloc(PL);                     // uhi+ulo
    float* rowpart = alloc((size_t)40 * N_);
    float* colpart = alloc((size_t)40 * N_);
    float* rowinv = alloc(N_);
    float* colinv = alloc(N_);
    float* sf1part = alloc((size_t)16 * N_);
    float* sf1 = alloc(N_);
    float* sf2 = alloc(N_);
    float* bnmu = alloc(DF_);
    float* bnrstd = alloc(DF_);
    float* lgpart = alloc((size_t)B_ * 5 * 4);
    ushort_t* Bhi = (ushort_t*)alloc(262144);       // Whh frags hi (1 MB)
    ushort_t* Blo = (ushort_t*)alloc(262144);
    ushort_t* Fhi = (ushort_t*)alloc(262144);       // Wih frags hi (1 MB)
    ushort_t* Flo = (ushort_t*)alloc(262144);
    ushort_t* fragbuf = (ushort_t*)alloc(131072);
    int* flags = (int*)alloc(1024);
    ushort_t* Ebf = (ushort_t*)alloc((size_t)N_ * N_ / 2);   // 52 MB bf16 E

    ushort_t* ehi = (ushort_t*)eplanes;
    ushort_t* elo = ehi + (size_t)2 * N_ * E_;
    ushort_t* Rthi = (ushort_t*)Rtplanes;
    ushort_t* Rtlo = Rthi + 512 * 512;
    ushort_t* o1hi = (ushort_t*)planesA;
    ushort_t* o1lo = o1hi + PL;
    ushort_t* o2hi = (ushort_t*)planesO2;
    ushort_t* o2lo = o2hi + PL;
    ushort_t* uhi = (ushort_t*)planesU;
    ushort_t* ulo = uhi + PL;

    k_prep<<<15425, 256, 0, stream>>>(arg1, arg2, table, tE1, tE2,
                                      Wih_f, Wih_b, bih_f, bhh_f, bih_b, bhh_b,
                                      R, Whh_f, Whh_b,
                                      ehi, elo, bcat, Rthi, Rtlo,
                                      Bhi, Blo, Fhi, Flo, fragbuf, flags, rel);
    // LSTM with fused xg (e*Wih computed in-kernel on the idle MFMA pipe)
    k_lstm10<<<256, 256, 0, stream>>>(ehi, elo, Bhi, Blo, Fhi, Flo, bcat,
                                      o1hi, o1lo, o2hi, o2lo, fragbuf, flags);
    // u = o1 @ R (split-bf16), epilogue emits u planes
    k_gemm_bf<<<160, 256, 0, stream>>>(
        o1hi, o1lo, Rthi, Rtlo, nullptr, nullptr, uhi, ulo, N_, 512, 512);
    k_bigm<<<1600, 256, 0, stream>>>(
        uhi, ulo, o2hi, o2lo, rel, Ebf, rowpart, colpart);
    k_redsum<<<(N_ + 255) / 256, 256, 0, stream>>>(rowpart, colpart, rowinv, colinv);
    k_sfboth<<<N_ + 160, 256, 0, stream>>>(Ebf, rowinv, colinv, sf1part, sf2);
    k_sf1red<<<(N_ + 255) / 256, 256, 0, stream>>>(sf1part, sf1);
    k_bnstats<<<DF_ / 256, 256, 0, stream>>>(o1hi, o1lo, o2hi, o2lo, sf1, sf2,
                                             bnmu, bnrstd);
    k_logits1<<<dim3(B_, 5), 256, 0, stream>>>(o1hi, o1lo, o2hi, o2lo, sf1, sf2,
                                               bnmu, bnrstd, gamma, beta, fcW, lgpart);
    k_logits2<<<B_, 64, 0, stream>>>(lgpart, fcb, dout);
}

// Round 17
// 619.591 us; speedup vs baseline: 1.0801x; 1.0801x over previous
//
#include <hip/hip_runtime.h>
#include <cstddef>
#include <cstdint>

typedef unsigned short ushort_t;

constexpr int B_ = 64, L_ = 80, E_ = 256, H_ = 256, C_ = 4, DT_ = 100;
constexpr int N_ = B_ * L_;          // 5120
constexpr int G4_ = 4 * H_;          // 1024
constexpr int DH2_ = 2 * H_;         // 512
constexpr int DF_ = 4 * L_ * H_;     // 81920
constexpr float EPS_ = 1e-5f;
constexpr int FB_USH = 8192;         // ushorts per (grp,par) fragment region (16 KB)

typedef short s8v __attribute__((ext_vector_type(8)));
typedef float f4v __attribute__((ext_vector_type(4)));
typedef ushort_t us8 __attribute__((ext_vector_type(8)));

__device__ inline ushort_t f2bf_rn(float x) {
    uint32_t u = __builtin_bit_cast(uint32_t, x);
    uint32_t r = (u + 0x7fffu + ((u >> 16) & 1u)) >> 16;
    return (ushort_t)r;
}
__device__ inline float bf2f(ushort_t h) {
    uint32_t u = ((uint32_t)h) << 16;
    return __builtin_bit_cast(float, u);
}
__device__ inline float bf2f_lo(uint32_t u) { return __builtin_bit_cast(float, u << 16); }
__device__ inline float bf2f_hi(uint32_t u) { return __builtin_bit_cast(float, u & 0xffff0000u); }
__device__ inline float rcpf(float x) { return __builtin_amdgcn_rcpf(x); }
__device__ inline float sigm(float x) { return rcpf(1.f + __expf(-x)); }
__device__ inline float tanh_fast(float x) {
    float e2 = __expf(2.f * x);
    return 1.f - 2.f * rcpf(1.f + e2);
}

#define MFMA_B16(a, b, c) __builtin_amdgcn_mfma_f32_16x16x32_bf16((a), (b), (c), 0, 0, 0)

// ---------------------------------------------------------------------------
// Merged preprocessing: embed (blocks 0..10239), pack Wcat/bcat/Rt
// (10240..12287), pack Whh fragments (12288..14335), init fragbuf/flags
// (14336..14399), rel (14400).
__global__ void k_prep(const int* __restrict__ arg1, const int* __restrict__ arg2,
                       const float* __restrict__ table,
                       const float* __restrict__ tE1, const float* __restrict__ tE2,
                       const float* __restrict__ Wih_f, const float* __restrict__ Wih_b,
                       const float* __restrict__ bih_f, const float* __restrict__ bhh_f,
                       const float* __restrict__ bih_b, const float* __restrict__ bhh_b,
                       const float* __restrict__ R,
                       const float* __restrict__ Whh_f, const float* __restrict__ Whh_b,
                       ushort_t* __restrict__ ehi, ushort_t* __restrict__ elo,
                       ushort_t* __restrict__ Wchi, ushort_t* __restrict__ Wclo,
                       float* __restrict__ bcat,
                       ushort_t* __restrict__ Rthi, ushort_t* __restrict__ Rtlo,
                       ushort_t* __restrict__ Bhi, ushort_t* __restrict__ Blo,
                       ushort_t* __restrict__ fragbuf, int* __restrict__ flags,
                       float* __restrict__ rel) {
    __shared__ float m1[80], m2[80];
    int blk = blockIdx.x;
    int tid = threadIdx.x;
    if (blk < 10240) {
        int r = blk;
        int rr = (r >= N_) ? (r - N_) : r;
        int idx = (r >= N_) ? arg2[rr] : arg1[rr];
        float v = table[(size_t)idx * E_ + tid];
        ushort_t h = f2bf_rn(v);
        ehi[(size_t)r * E_ + tid] = h;
        elo[(size_t)r * E_ + tid] = f2bf_rn(v - bf2f(h));
    } else if (blk < 12288) {
        int i = (blk - 10240) * 256 + tid;
        if (i < 2 * G4_ * E_) {
            float v = (i < G4_ * E_) ? Wih_f[i] : Wih_b[i - G4_ * E_];
            ushort_t h = f2bf_rn(v);
            Wchi[i] = h;
            Wclo[i] = f2bf_rn(v - bf2f(h));
        }
        if (i < 2 * G4_)
            bcat[i] = (i < G4_) ? (bih_f[i] + bhh_f[i]) : (bih_b[i - G4_] + bhh_b[i - G4_]);
        if (i < 512 * 512) {
            int m = i >> 9, k = i & 511;
            float v = R[k * 512 + m];
            ushort_t h = f2bf_rn(v);
            Rthi[i] = h;
            Rtlo[i] = f2bf_rn(v - bf2f(h));
        }
    } else if (blk < 14336) {
        int idx = (blk - 12288) * 256 + tid;
        int e = idx & 7;
        int lane = (idx >> 3) & 63;
        int g = (idx >> 9) & 3;
        int kt = (idx >> 11) & 7;
        int w = (idx >> 14) & 15;
        int d = idx >> 18;
        int c = lane & 15, q = lane >> 4;
        int row = g * 256 + w * 16 + c;
        int k = kt * 32 + q * 8 + e;
        const float* W = d ? Whh_b : Whh_f;
        float v = W[row * 256 + k];
        ushort_t hi = f2bf_rn(v);
        Bhi[idx] = hi;
        Blo[idx] = f2bf_rn(v - bf2f(hi));
    } else if (blk < 14400) {
        int i = (blk - 14336) * 256 + tid;
        if (i < 1024) flags[i] = 0;
        uint4* p = (uint4*)fragbuf;
        for (int jj = i; jj < 32768; jj += 64 * 256)
            p[jj] = make_uint4(0u, 0u, 0u, 0u);
    } else {
        if (tid < 80) {
            float s = 0.f;
            for (int k = 0; k < DT_; ++k) s += tE1[tid * DT_ + k];
            m1[tid] = s * (1.0f / DT_);
        } else if (tid < 160) {
            int i = tid - 80;
            float s = 0.f;
            for (int k = 0; k < DT_; ++k) s += tE2[i * DT_ + k];
            m2[i] = s * (1.0f / DT_);
        }
        __syncthreads();
        for (int idx = tid; idx < 80 * 80; idx += 256)
            rel[idx] = tanhf(m1[idx / 80] - m2[idx % 80]);
    }
}

// ---------------------------------------------------------------------------
// Persistent flag-dataflow LSTM v9c (PROVEN OPTIMUM of the sync variants).
// Protocol: block barrier D -> single block flag -> ONE polling wave (tid<16)
// -> barrier A. Per-wave/distributed variants regressed 3x (R7, R10, R14);
// fusing the xg GEMM in regressed too (R16). Do not modify.
__global__ __launch_bounds__(256, 2) void k_lstm9c(
        const float* __restrict__ xg,
        const ushort_t* __restrict__ Bhi, const ushort_t* __restrict__ Blo,
        ushort_t* __restrict__ o1hi, ushort_t* __restrict__ o1lo,
        ushort_t* __restrict__ o2hi, ushort_t* __restrict__ o2lo,
        ushort_t* __restrict__ fragbuf, int* __restrict__ flags) {
    const int bid = blockIdx.x;          // 0..255
    const int s = bid & 15;
    const int cg = (bid >> 4) & 7;
    const int d = bid >> 7;
    const int tid = threadIdx.x;         // 0..255
    const int g = tid >> 6, lane = tid & 63;
    const int c16 = lane & 15, qq = lane >> 4;

    __shared__ __align__(16) ushort_t Abuf[8192];   // 16 KB
    __shared__ float pre[4][16][16];                // 4 KB

    s8v bh[8], bl[8];
    {
        const s8v* BH = (const s8v*)Bhi;
        const s8v* BL = (const s8v*)Blo;
        int base = (d * 16 + s) * 2048 + g * 64 + lane;
        #pragma unroll
        for (int kt = 0; kt < 8; ++kt) {
            bh[kt] = BH[base + kt * 256];
            bl[kt] = BL[base + kt * 256];
        }
    }

    const int c_loc = tid >> 4, j = tid & 15;
    const int kglob = s * 16 + j;
    const int p_kt = kglob >> 5;
    const int p_q = (kglob & 31) >> 3, p_e = kglob & 7;
    const int p_lane = c_loc | (p_q << 4);
    const int fb_off = (p_kt * 64 + p_lane) * 8 + p_e;     // < 4096
    const int cc = cg * 16 + c_loc;
    const int w = cc >> 6, bb = cc & 63;
    ushort_t* ophi = w ? o2hi : o1hi;
    ushort_t* oplo = w ? o2lo : o1lo;
    float cst = 0.f;

    const int grp = bid >> 4;
    int* gflags = flags + grp * 16;
    const size_t fbbase = (size_t)grp * 2 * FB_USH;

    for (int t = 0; t < L_; ++t) {
        int l = d ? (L_ - 1 - t) : t;

        float xv[4];
        {
            const float* xp = xg + (size_t)(w * N_ + bb * L_ + l) * 2048
                              + d * 1024 + kglob;
            #pragma unroll
            for (int gg = 0; gg < 4; ++gg) xv[gg] = xp[gg * 256];
        }

        if (t > 0) {
            if (tid < 16) {
                while (__hip_atomic_load(&gflags[tid], __ATOMIC_RELAXED,
                                         __HIP_MEMORY_SCOPE_AGENT) < t)
                    __builtin_amdgcn_s_sleep(2);
            }
            __syncthreads();             // bar A: all producers done
        }

        {
            const unsigned long long* src = (const unsigned long long*)(fragbuf
                + fbbase + (size_t)(t & 1) * FB_USH);
            unsigned long long* dst = (unsigned long long*)Abuf;
            #pragma unroll
            for (int r = 0; r < 8; ++r)
                dst[r * 256 + tid] = __hip_atomic_load(
                    &src[r * 256 + tid], __ATOMIC_RELAXED,
                    __HIP_MEMORY_SCOPE_AGENT);
        }
        __syncthreads();                 // bar B: A staged

        f4v acc = {0.f, 0.f, 0.f, 0.f};
        {
            const s8v* AH = (const s8v*)&Abuf[0];
            const s8v* AL = (const s8v*)&Abuf[4096];
            #pragma unroll
            for (int kt = 0; kt < 8; ++kt) {
                s8v ah = AH[kt * 64 + lane];
                s8v al = AL[kt * 64 + lane];
                acc = MFMA_B16(ah, bh[kt], acc);
                acc = MFMA_B16(ah, bl[kt], acc);
                acc = MFMA_B16(al, bh[kt], acc);
            }
        }
        #pragma unroll
        for (int r = 0; r < 4; ++r)
            pre[g][qq * 4 + r][c16] = acc[r];
        __syncthreads();                 // bar C: pre visible

        ushort_t hh, hl;
        size_t oidx;
        {
            float pi = pre[0][c_loc][j] + xv[0];
            float pf = pre[1][c_loc][j] + xv[1];
            float pg = pre[2][c_loc][j] + xv[2];
            float po = pre[3][c_loc][j] + xv[3];
            float si = sigm(pi), sf_ = sigm(pf), so = sigm(po);
            cst = sf_ * cst + si * tanh_fast(pg);
            float h = so * tanh_fast(cst);
            oidx = (size_t)(bb * L_ + l) * DH2_ + d * H_ + kglob;
            hh = f2bf_rn(h);
            hl = f2bf_rn(h - bf2f(hh));
            ushort_t* fbn = fragbuf + fbbase + (size_t)((t + 1) & 1) * FB_USH;
            __hip_atomic_store(&fbn[fb_off], hh, __ATOMIC_RELAXED,
                               __HIP_MEMORY_SCOPE_AGENT);
            __hip_atomic_store(&fbn[4096 + fb_off], hl, __ATOMIC_RELAXED,
                               __HIP_MEMORY_SCOPE_AGENT);
        }
        __syncthreads();                 // bar D: frag stores drained block-wide

        if (tid == 0)
            __hip_atomic_store(&flags[bid], t + 1, __ATOMIC_RELAXED,
                               __HIP_MEMORY_SCOPE_AGENT);

        ophi[oidx] = hh;                 // off-critical-path
        oplo[oidx] = hl;
    }
}

// ---------------------------------------------------------------------------
// Generic split-bf16 MFMA GEMM: C = A * Bt^T (+bias). 128x128 tile, 1-D grid
// with XCD-chunked swizzle.
__global__ __launch_bounds__(256) void k_gemm_bf(
        const ushort_t* __restrict__ Ahi, const ushort_t* __restrict__ Alo,
        const ushort_t* __restrict__ Bthi, const ushort_t* __restrict__ Btlo,
        const float* __restrict__ bias, float* __restrict__ Cout,
        ushort_t* __restrict__ Couthi, ushort_t* __restrict__ Coutlo,
        int M, int Nn, int K) {
    __shared__ ushort_t smpool[4][4096];        // 32 KB
    const int tid = threadIdx.x;
    const int w = tid >> 6, lane = tid & 63;
    const int wr = w >> 1, wc = w & 1;
    const int c16 = lane & 15, q4 = lane >> 4;
    const int nbx = Nn >> 7;
    const int cpx = ((M >> 7) * nbx) >> 3;
    const int fid = blockIdx.x;
    const int swz = (fid & 7) * cpx + (fid >> 3);
    const int bx = swz % nbx, by = swz / nbx;
    const int r0 = by * 128, c0 = bx * 128;

    f4v acc[4][4] = {};
    const ushort_t* planes[4] = {
        Ahi + (size_t)r0 * K, Alo + (size_t)r0 * K,
        Bthi + (size_t)c0 * K, Btlo + (size_t)c0 * K };

    for (int kk = 0; kk < K; kk += 32) {
        #pragma unroll
        for (int p = 0; p < 4; ++p) {
            const ushort_t* src = planes[p] + kk;
            #pragma unroll
            for (int it = 0; it < 2; ++it) {
                int idx = it * 256 + tid;
                int row = idx >> 2, q = idx & 3;
                *(us8*)&smpool[p][(q * 128 + row) * 8] =
                    *(const us8*)&src[(size_t)row * K + q * 8];
            }
        }
        __syncthreads();
        s8v ah[4], al[4], bhv[4], blv[4];
        #pragma unroll
        for (int mi = 0; mi < 4; ++mi) {
            int ar = wr * 64 + mi * 16 + c16;
            ah[mi] = *(const s8v*)&smpool[0][(q4 * 128 + ar) * 8];
            al[mi] = *(const s8v*)&smpool[1][(q4 * 128 + ar) * 8];
        }
        #pragma unroll
        for (int ni = 0; ni < 4; ++ni) {
            int br = wc * 64 + ni * 16 + c16;
            bhv[ni] = *(const s8v*)&smpool[2][(q4 * 128 + br) * 8];
            blv[ni] = *(const s8v*)&smpool[3][(q4 * 128 + br) * 8];
        }
        #pragma unroll
        for (int mi = 0; mi < 4; ++mi)
            #pragma unroll
            for (int ni = 0; ni < 4; ++ni) {
                acc[mi][ni] = MFMA_B16(ah[mi], bhv[ni], acc[mi][ni]);
                acc[mi][ni] = MFMA_B16(ah[mi], blv[ni], acc[mi][ni]);
                acc[mi][ni] = MFMA_B16(al[mi], bhv[ni], acc[mi][ni]);
            }
        __syncthreads();
    }
    #pragma unroll
    for (int mi = 0; mi < 4; ++mi)
        #pragma unroll
        for (int rg = 0; rg < 4; ++rg) {
            int row = r0 + wr * 64 + mi * 16 + q4 * 4 + rg;
            #pragma unroll
            for (int ni = 0; ni < 4; ++ni) {
                int col = c0 + wc * 64 + ni * 16 + c16;
                float v = acc[mi][ni][rg] + (bias ? bias[col] : 0.f);
                size_t idx = (size_t)row * Nn + col;
                if (Couthi) {
                    ushort_t h = f2bf_rn(v);
                    Couthi[idx] = h;
                    Coutlo[idx] = f2bf_rn(v - bf2f(h));
                } else {
                    Cout[idx] = v;
                }
            }
        }
}

// ---------------------------------------------------------------------------
// MFMA k_big: E = exp(tanh(u t2^T) + kg) stored bf16; sums of ROUNDED values.
__global__ __launch_bounds__(256) void k_bigm(
        const ushort_t* __restrict__ uhi, const ushort_t* __restrict__ ulo,
        const ushort_t* __restrict__ vhi, const ushort_t* __restrict__ vlo,
        const float* __restrict__ rel, ushort_t* __restrict__ Ebf,
        float* __restrict__ rowpart, float* __restrict__ colpart) {
    __shared__ ushort_t smpool[4][4096];        // 32 KB
    const int tid = threadIdx.x;
    const int w = tid >> 6, lane = tid & 63;
    const int wr = w >> 1, wc = w & 1;
    const int c16 = lane & 15, q4 = lane >> 4;
    const int fid = blockIdx.x;                 // 1600 = 8 * 200
    const int swz = (fid & 7) * 200 + (fid >> 3);
    const int bx = swz % 40, by = swz / 40;
    const int r0 = by * 128, c0 = bx * 128;

    f4v acc[4][4] = {};
    const ushort_t* planes[4] = {
        uhi + (size_t)r0 * DH2_, ulo + (size_t)r0 * DH2_,
        vhi + (size_t)c0 * DH2_, vlo + (size_t)c0 * DH2_ };

    for (int kk = 0; kk < 16; ++kk) {
        #pragma unroll
        for (int p = 0; p < 4; ++p) {
            const ushort_t* src = planes[p] + kk * 32;
            #pragma unroll
            for (int it = 0; it < 2; ++it) {
                int idx = it * 256 + tid;
                int row = idx >> 2, q = idx & 3;
                *(us8*)&smpool[p][(q * 128 + row) * 8] =
                    *(const us8*)&src[(size_t)row * DH2_ + q * 8];
            }
        }
        __syncthreads();
        s8v ah[4], al[4], bhv[4], blv[4];
        #pragma unroll
        for (int mi = 0; mi < 4; ++mi) {
            int ar = wr * 64 + mi * 16 + c16;
            ah[mi] = *(const s8v*)&smpool[0][(q4 * 128 + ar) * 8];
            al[mi] = *(const s8v*)&smpool[1][(q4 * 128 + ar) * 8];
        }
        #pragma unroll
        for (int ni = 0; ni < 4; ++ni) {
            int br = wc * 64 + ni * 16 + c16;
            bhv[ni] = *(const s8v*)&smpool[2][(q4 * 128 + br) * 8];
            blv[ni] = *(const s8v*)&smpool[3][(q4 * 128 + br) * 8];
        }
        #pragma unroll
        for (int mi = 0; mi < 4; ++mi)
            #pragma unroll
            for (int ni = 0; ni < 4; ++ni) {
                acc[mi][ni] = MFMA_B16(ah[mi], bhv[ni], acc[mi][ni]);
                acc[mi][ni] = MFMA_B16(ah[mi], blv[ni], acc[mi][ni]);
                acc[mi][ni] = MFMA_B16(al[mi], bhv[ni], acc[mi][ni]);
            }
        __syncthreads();
    }

    float* rowred = (float*)&smpool[0][0];      // [128][32]
    float* colred = rowred + 128 * 32;          // [128][8]

    int gcolv[4], bjv[4], ljv[4];
    #pragma unroll
    for (int ni = 0; ni < 4; ++ni) {
        int coll = wc * 64 + ni * 16 + c16;
        gcolv[ni] = c0 + coll;
        bjv[ni] = gcolv[ni] / 80;
        ljv[ni] = gcolv[ni] - bjv[ni] * 80;
    }
    float csumv[4] = {0.f, 0.f, 0.f, 0.f};
    #pragma unroll
    for (int mi = 0; mi < 4; ++mi) {
        #pragma unroll
        for (int rg = 0; rg < 4; ++rg) {
            int rowl = wr * 64 + mi * 16 + q4 * 4 + rg;
            int grow = r0 + rowl;
            int bi = grow / 80, li = grow - bi * 80;
            float rsum = 0.f;
            #pragma unroll
            for (int ni = 0; ni < 4; ++ni) {
                float v = tanhf(acc[mi][ni][rg]);
                if (bi == bjv[ni]) v += rel[li * 80 + ljv[ni]];
                ushort_t eb = f2bf_rn(__expf(v));
                Ebf[(size_t)grow * N_ + gcolv[ni]] = eb;
                float er = bf2f(eb);
                rsum += er;
                csumv[ni] += er;
            }
            rowred[rowl * 32 + wc * 16 + c16] = rsum;
        }
    }
    #pragma unroll
    for (int ni = 0; ni < 4; ++ni) {
        int coll = wc * 64 + ni * 16 + c16;
        colred[coll * 8 + wr * 4 + q4] = csumv[ni];
    }
    __syncthreads();
    if (tid < 128) {
        float ssum = 0.f;
        #pragma unroll
        for (int t = 0; t < 32; ++t) ssum += rowred[tid * 32 + t];
        rowpart[(size_t)bx * N_ + r0 + tid] = ssum;
    } else {
        int c = tid - 128;
        float ssum = 0.f;
        #pragma unroll
        for (int t = 0; t < 8; ++t) ssum += colred[c * 8 + t];
        colpart[(size_t)by * N_ + c0 + c] = ssum;
    }
}

// ---------------------------------------------------------------------------
__global__ void k_redsum(const float* __restrict__ rowpart, const float* __restrict__ colpart,
                         float* __restrict__ rowinv, float* __restrict__ colinv) {
    int i = blockIdx.x * blockDim.x + threadIdx.x;
    if (i < N_) {
        float rs = 0.f, cs = 0.f;
        for (int t = 0; t < 40; ++t) {
            rs += rowpart[(size_t)t * N_ + i];
            cs += colpart[(size_t)t * N_ + i];
        }
        rowinv[i] = 1.f / rs;
        colinv[i] = 1.f / cs;
    }
}

// ---------------------------------------------------------------------------
// Merged sf pass: blocks 0..5119 = sf2 rows (one block/row, LDS tree);
// blocks 5120..5279 = sf1 chunks (col-pair registers over 320-row chunks).
__global__ __launch_bounds__(256) void k_sfboth(
        const ushort_t* __restrict__ Ebf,
        const float* __restrict__ rowinv, const float* __restrict__ colinv,
        float* __restrict__ sf1part, float* __restrict__ sf2) {
    if (blockIdx.x < N_) {
        int i = blockIdx.x;
        const uint32_t* Erow = (const uint32_t*)(Ebf + (size_t)i * N_);
        float p = 0.f;
        #pragma unroll 2
        for (int j2 = threadIdx.x; j2 < N_ / 2; j2 += 256) {
            uint32_t u = Erow[j2];
            p += bf2f_lo(u) * colinv[j2 * 2] + bf2f_hi(u) * colinv[j2 * 2 + 1];
        }
        __shared__ float red[256];
        red[threadIdx.x] = p;
        __syncthreads();
        for (int ss = 128; ss > 0; ss >>= 1) {
            if (threadIdx.x < ss) red[threadIdx.x] += red[threadIdx.x + ss];
            __syncthreads();
        }
        if (threadIdx.x == 0) sf2[i] = red[0] * (1.f / N_);
    } else {
        int b2 = blockIdx.x - N_;                 // 0..159
        int cpb = b2 % 10, rc = b2 / 10;
        int cp = cpb * 256 + threadIdx.x;         // column pair 0..2559
        int r0 = rc * 320;
        float a0 = 0.f, a1 = 0.f;
        #pragma unroll 4
        for (int ii = 0; ii < 320; ++ii) {
            int row = r0 + ii;
            uint32_t u = *(const uint32_t*)(Ebf + (size_t)row * N_ + cp * 2);
            float rinv = rowinv[row];
            a0 += bf2f_lo(u) * rinv;
            a1 += bf2f_hi(u) * rinv;
        }
        sf1part[(size_t)rc * N_ + cp * 2] = a0;
        sf1part[(size_t)rc * N_ + cp * 2 + 1] = a1;
    }
}

__global__ void k_sf1red(const float* __restrict__ sf1part, float* __restrict__ sf1) {
    int jj = blockIdx.x * blockDim.x + threadIdx.x;
    if (jj < N_) {
        float s = 0.f;
        for (int t = 0; t < 16; ++t) s += sf1part[(size_t)t * N_ + jj];
        sf1[jj] = s * (1.f / N_);
    }
}

// ---------------------------------------------------------------------------
__global__ void k_bnstats(const ushort_t* __restrict__ o1hi, const ushort_t* __restrict__ o1lo,
                          const ushort_t* __restrict__ o2hi, const ushort_t* __restrict__ o2lo,
                          const float* __restrict__ sf1, const float* __restrict__ sf2,
                          float* __restrict__ bnmu, float* __restrict__ bnrstd) {
    int f = blockIdx.x * 256 + threadIdx.x;
    int seg = f / (L_ * DH2_);
    int rem = f - seg * (L_ * DH2_);
    int l = rem >> 9, hh = rem & 511;
    const ushort_t* phi = seg ? o2hi : o1hi;
    const ushort_t* plo = seg ? o2lo : o1lo;
    const float* sf = seg ? sf1 : sf2;
    float s = 0.f, s2 = 0.f;
    for (int b = 0; b < B_; ++b) {
        int row = b * L_ + l;
        size_t idx = (size_t)row * DH2_ + hh;
        float x = (bf2f(phi[idx]) + bf2f(plo[idx])) * sf[row];
        s += x;
        s2 += x * x;
    }
    float mu = s * (1.f / B_);
    float v = fmaxf(s2 * (1.f / B_) - mu * mu, 0.f);
    bnmu[f] = mu;
    bnrstd[f] = rsqrtf(v + EPS_);
}

// ---------------------------------------------------------------------------
__global__ __launch_bounds__(256) void k_logits1(
        const ushort_t* __restrict__ o1hi, const ushort_t* __restrict__ o1lo,
        const ushort_t* __restrict__ o2hi, const ushort_t* __restrict__ o2lo,
        const float* __restrict__ sf1, const float* __restrict__ sf2,
        const float* __restrict__ bnmu, const float* __restrict__ bnrstd,
        const float* __restrict__ gamma, const float* __restrict__ beta,
        const float* __restrict__ fcW, float* __restrict__ part) {
    int b = blockIdx.x, ch = blockIdx.y;
    int tid = threadIdx.x;
    int f0 = ch * (DF_ / 5);
    float acc[4] = {0.f, 0.f, 0.f, 0.f};
    for (int f = f0 + tid; f < f0 + DF_ / 5; f += 256) {
        int seg = f / (L_ * DH2_);
        int rem = f - seg * (L_ * DH2_);
        int l = rem >> 9, hh = rem & 511;
        int row = b * L_ + l;
        size_t idx = (size_t)row * DH2_ + hh;
        const ushort_t* phi = seg ? o2hi : o1hi;
        const ushort_t* plo = seg ? o2lo : o1lo;
        float val = (bf2f(phi[idx]) + bf2f(plo[idx])) * (seg ? sf1 : sf2)[row];
        float xn = (val - bnmu[f]) * bnrstd[f] * gamma[f] + beta[f];
        #pragma unroll
        for (int c = 0; c < 4; ++c) acc[c] += xn * fcW[(size_t)c * DF_ + f];
    }
    __shared__ float red[4][257];
    #pragma unroll
    for (int c = 0; c < 4; ++c) red[c][tid] = acc[c];
    __syncthreads();
    for (int ss = 128; ss > 0; ss >>= 1) {
        if (tid < ss)
            #pragma unroll
            for (int c = 0; c < 4; ++c) red[c][tid] += red[c][tid + ss];
        __syncthreads();
    }
    if (tid < 4) part[((size_t)b * 5 + ch) * 4 + tid] = red[tid][0];
}

__global__ void k_logits2(const float* __restrict__ part,
                          const float* __restrict__ fcb,
                          float* __restrict__ dout) {
    int b = blockIdx.x;
    if (threadIdx.x == 0) {
        float lg[4], mx = -1e30f;
        #pragma unroll
        for (int c = 0; c < 4; ++c) {
            float v = fcb[c];
            for (int ch = 0; ch < 5; ++ch) v += part[((size_t)b * 5 + ch) * 4 + c];
            lg[c] = v;
            mx = fmaxf(mx, v);
        }
        float se = 0.f;
        #pragma unroll
        for (int c = 0; c < 4; ++c) se += expf(lg[c] - mx);
        float lse = mx + logf(se);
        #pragma unroll
        for (int c = 0; c < 4; ++c) dout[b * 4 + c] = lg[c] - lse;
    }
}

// ---------------------------------------------------------------------------
extern "C" void kernel_launch(void* const* d_in, const int* in_sizes, int n_in,
                              void* d_out, int out_size, void* d_ws, size_t ws_size,
                              hipStream_t stream) {
    const int* arg1 = (const int*)d_in[0];
    const int* arg2 = (const int*)d_in[1];
    const float* tE1 = (const float*)d_in[3];
    const float* tE2 = (const float*)d_in[4];
    const float* table = (const float*)d_in[5];
    const float* Wih_f = (const float*)d_in[6];
    const float* Whh_f = (const float*)d_in[7];
    const float* bih_f = (const float*)d_in[8];
    const float* bhh_f = (const float*)d_in[9];
    const float* Wih_b = (const float*)d_in[10];
    const float* Whh_b = (const float*)d_in[11];
    const float* bih_b = (const float*)d_in[12];
    const float* bhh_b = (const float*)d_in[13];
    const float* R = (const float*)d_in[14];
    const float* gamma = (const float*)d_in[15];
    const float* beta = (const float*)d_in[16];
    const float* fcW = (const float*)d_in[17];
    const float* fcb = (const float*)d_in[18];
    float* dout = (float*)d_out;

    float* ws = (float*)d_ws;
    size_t off = 0;
    auto alloc = [&](size_t n) { float* p = ws + off; off += n; return p; };

    constexpr size_t PL = (size_t)N_ * DH2_;        // 2,621,440 elements/plane

    float* rel = alloc(80 * 80);
    float* eplanes = alloc((size_t)2 * N_ * E_);    // ehi+elo; then o2hi+o2lo
    float* Wcplanes = alloc((size_t)2 * G4_ * E_);
    float* bcat = alloc(2 * G4_);
    float* Rtplanes = alloc((size_t)262144);
    float* planesA = alloc(PL);                     // o1hi+o1lo
    float* planesU = alloc(PL);                     // uhi+ulo
    float* rowpart = alloc((size_t)40 * N_);
    float* colpart = alloc((size_t)40 * N_);
    float* rowinv = alloc(N_);
    float* colinv = alloc(N_);
    float* sf1part = alloc((size_t)16 * N_);
    float* sf1 = alloc(N_);
    float* sf2 = alloc(N_);
    float* bnmu = alloc(DF_);
    float* bnrstd = alloc(DF_);
    float* lgpart = alloc((size_t)B_ * 5 * 4);
    ushort_t* Bhi = (ushort_t*)alloc(262144);
    ushort_t* Blo = (ushort_t*)alloc(262144);
    ushort_t* fragbuf = (ushort_t*)alloc(131072);
    int* flags = (int*)alloc(1024);
    float* xg = alloc((size_t)N_ * N_);             // f32 xg; later bf16 Ebuf
    ushort_t* Ebf = (ushort_t*)xg;

    ushort_t* ehi = (ushort_t*)eplanes;
    ushort_t* elo = ehi + (size_t)2 * N_ * E_;
    ushort_t* Wchi = (ushort_t*)Wcplanes;
    ushort_t* Wclo = Wchi + (size_t)2 * G4_ * E_;
    ushort_t* Rthi = (ushort_t*)Rtplanes;
    ushort_t* Rtlo = Rthi + 512 * 512;
    ushort_t* o1hi = (ushort_t*)planesA;
    ushort_t* o1lo = o1hi + PL;
    ushort_t* uhi = (ushort_t*)planesU;
    ushort_t* ulo = uhi + PL;
    ushort_t* o2hi = ehi;                           // reuse eplanes (ehi dead)
    ushort_t* o2lo = elo;

    k_prep<<<14401, 256, 0, stream>>>(arg1, arg2, table, tE1, tE2,
                                      Wih_f, Wih_b, bih_f, bhh_f, bih_b, bhh_b,
                                      R, Whh_f, Whh_b,
                                      ehi, elo, Wchi, Wclo, bcat, Rthi, Rtlo,
                                      Bhi, Blo, fragbuf, flags, rel);
    k_gemm_bf<<<1280, 256, 0, stream>>>(
        ehi, elo, Wchi, Wclo, bcat, xg, nullptr, nullptr, 2 * N_, 2048, E_);
    k_lstm9c<<<256, 256, 0, stream>>>(xg, Bhi, Blo,
                                      o1hi, o1lo, o2hi, o2lo, fragbuf, flags);
    k_gemm_bf<<<160, 256, 0, stream>>>(
        o1hi, o1lo, Rthi, Rtlo, nullptr, nullptr, uhi, ulo, N_, 512, 512);
    k_bigm<<<1600, 256, 0, stream>>>(
        uhi, ulo, o2hi, o2lo, rel, Ebf, rowpart, colpart);
    k_redsum<<<(N_ + 255) / 256, 256, 0, stream>>>(rowpart, colpart, rowinv, colinv);
    k_sfboth<<<N_ + 160, 256, 0, stream>>>(Ebf, rowinv, colinv, sf1part, sf2);
    k_sf1red<<<(N_ + 255) / 256, 256, 0, stream>>>(sf1part, sf1);
    k_bnstats<<<DF_ / 256, 256, 0, stream>>>(o1hi, o1lo, o2hi, o2lo, sf1, sf2,
                                             bnmu, bnrstd);
    k_logits1<<<dim3(B_, 5), 256, 0, stream>>>(o1hi, o1lo, o2hi, o2lo, sf1, sf2,
                                               bnmu, bnrstd, gamma, beta, fcW, lgpart);
    k_logits2<<<B_, 64, 0, stream>>>(lgpart, fcb, dout);
}